// Round 2
// baseline (84.460 us; speedup 1.0000x reference)
//
#include <hip/hip_runtime.h>
#include <hip/hip_bf16.h>

// ---------------------------------------------------------------------------
// Kernel 1: build the fixed 16x16 unitary U from `weights` (L layers of
// per-qubit RY,RZ then CNOT(0,1), CNOT(2,3)). Thread j evolves basis state |j>
// giving column j. Layout in ws: U_real[a*16+b] at [0..255], U_imag at [256..511].
// Wire q maps to bit (3-q) of the flat index (stride 8>>q), matching the
// reference's (n,2,2,2,2) axis order. (Verified absmax=0.0 in round 1.)
// ---------------------------------------------------------------------------
__global__ __launch_bounds__(64) void setup_U_kernel(const float* __restrict__ w,
                                                     int L, float* __restrict__ U)
{
    const int j = threadIdx.x;
    if (j >= 16) return;

    float ar[16], ai[16];
#pragma unroll
    for (int k = 0; k < 16; ++k) { ar[k] = (k == j) ? 1.f : 0.f; ai[k] = 0.f; }

    for (int l = 0; l < L; ++l) {
#pragma unroll
        for (int q = 0; q < 4; ++q) {
            const float thy = w[l * 8 + q * 2 + 0];
            const float thz = w[l * 8 + q * 2 + 1];
            float cy, sy, cz, sz;
            __sincosf(0.5f * thy, &sy, &cy);
            __sincosf(0.5f * thz, &sz, &cz);
            const int st = 8 >> q;
#pragma unroll
            for (int idx = 0; idx < 16; ++idx) {
                if ((idx & st) == 0) {
                    const int i1 = idx + st;
                    const float a0r = ar[idx], a1r = ar[i1];
                    const float a0i = ai[idx], a1i = ai[i1];
                    ar[idx] = cy * a0r - sy * a1r;  ar[i1] = sy * a0r + cy * a1r;
                    ai[idx] = cy * a0i - sy * a1i;  ai[i1] = sy * a0i + cy * a1i;
                }
            }
#pragma unroll
            for (int idx = 0; idx < 16; ++idx) {
                const float r = ar[idx], im = ai[idx];
                if ((idx & st) == 0) {
                    ar[idx] = r * cz + im * sz;
                    ai[idx] = im * cz - r * sz;
                } else {
                    ar[idx] = r * cz - im * sz;
                    ai[idx] = im * cz + r * sz;
                }
            }
        }
#pragma unroll
        for (int idx = 0; idx < 16; ++idx) {
            if ((idx & 8) && !(idx & 4)) {
                const int i2 = idx | 4;
                float tr = ar[idx], ti = ai[idx];
                ar[idx] = ar[i2]; ai[idx] = ai[i2];
                ar[i2] = tr;      ai[i2] = ti;
            }
        }
#pragma unroll
        for (int idx = 0; idx < 16; ++idx) {
            if ((idx & 2) && !(idx & 1)) {
                const int i2 = idx | 1;
                float tr = ar[idx], ti = ai[idx];
                ar[idx] = ar[i2]; ai[idx] = ai[i2];
                ar[i2] = tr;      ai[i2] = ti;
            }
        }
    }

#pragma unroll
    for (int a = 0; a < 16; ++a) {
        U[a * 16 + j]       = ar[a];
        U[256 + a * 16 + j] = ai[a];
    }
}

// ---------------------------------------------------------------------------
// Kernel 2: fused per-image pipeline, amplitude-parallel.
// Block = 256 threads = 16 groups of 16 lanes. Group g handles patch
// (iter*16+g); lane a within the group owns amplitude row a, with U row a
// resident in 32 VGPRs (loaded once). Per patch: psi via LDS broadcast
// (ds_read_b128, conflict-free), 32 FMA matvec, |A|^2, then a 4-stage signed
// Walsh-Hadamard butterfly over the 16 lanes gives z_q at lane (8>>q).
// Phase B: GEMV 784->10 + log_softmax (unchanged, validated).
// ---------------------------------------------------------------------------
#define NP 196      // patches per image
#define PSTRIDE 20  // psi row stride in floats (80 B: 16B-aligned, bank-spread)

__global__ __launch_bounds__(256) void quanv_fused_kernel(
    const float* __restrict__ x, const float* __restrict__ Wc,
    const float* __restrict__ bc, const float* __restrict__ U,
    float* __restrict__ out)
{
    const int b   = blockIdx.x;
    const int tid = threadIdx.x;
    const int a   = tid & 15;   // amplitude row
    const int g   = tid >> 4;   // group (patch slot)

    __shared__ __align__(16) float psi_s[NP][PSTRIDE];
    __shared__ float qf[784];
    __shared__ float red[40];
    __shared__ float logits_s[10];

    // ---- U row a -> registers (once; 8x global_load_dwordx4, L2-hot)
    float Ur[16], Ui[16];
    {
        const float4* U4 = (const float4*)U;
#pragma unroll
        for (int j = 0; j < 4; ++j) {
            const float4 r  = U4[a * 4 + j];
            const float4 im = U4[64 + a * 4 + j];
            Ur[4 * j + 0] = r.x;  Ur[4 * j + 1] = r.y;
            Ur[4 * j + 2] = r.z;  Ur[4 * j + 3] = r.w;
            Ui[4 * j + 0] = im.x; Ui[4 * j + 1] = im.y;
            Ui[4 * j + 2] = im.z; Ui[4 * j + 3] = im.w;
        }
    }

    // ---- Pre-pass: psi[16] per patch -> LDS (threads 0..195)
    if (tid < NP) {
        const int pi = tid / 14, pj = tid % 14;
        const float* xb = x + b * 784 + pi * 56 + pj * 2;
        const float d0 = xb[0], d1 = xb[1], d2 = xb[28], d3 = xb[29];

        float c0, s0, c1, s1, c2, s2, c3, s3;
        __sincosf(0.5f * d0, &s0, &c0);
        __sincosf(0.5f * d1, &s1, &c1);
        __sincosf(0.5f * d2, &s2, &c2);
        __sincosf(0.5f * d3, &s3, &c3);

        const float w0[2] = {c0, s0}, w1[2] = {c1, s1};
        const float w2[2] = {c2, s2}, w3[2] = {c3, s3};
        float4* dst = (float4*)&psi_s[tid][0];
#pragma unroll
        for (int i0 = 0; i0 < 2; ++i0)
#pragma unroll
            for (int i1 = 0; i1 < 2; ++i1) {
                const float ab = w0[i0] * w1[i1];
#pragma unroll
                for (int i2 = 0; i2 < 2; ++i2) {
                    const float abc = ab * w2[i2];
                    float4 v;
                    v.x = abc * w3[0];  // i3=0 (paired as [i2][i3] within float4)
                    v.y = abc * w3[1];
                    (void)v;
                    // fill two elements at a time: idx = i0*8+i1*4+i2*2+i3
                    psi_s[tid][i0 * 8 + i1 * 4 + i2 * 2 + 0] = abc * w3[0];
                    psi_s[tid][i0 * 8 + i1 * 4 + i2 * 2 + 1] = abc * w3[1];
                }
            }
        (void)dst;
    }

    // ---- WHT sign factors: sgn[s] = (lane & (1<<s)) ? -1 : +1
    float sgn[4];
#pragma unroll
    for (int s = 0; s < 4; ++s) sgn[s] = (tid & (1 << s)) ? -1.f : 1.f;

    __syncthreads();

    // ---- Main loop: 13 iterations x 16 groups = 208 slots (>=196 clamped)
#pragma unroll 1
    for (int it = 0; it < 13; ++it) {
        const int p  = it * 16 + g;
        const int pc = (p < NP) ? p : (NP - 1);

        float psi[16];
        {
            const float4* prow = (const float4*)&psi_s[pc][0];
#pragma unroll
            for (int j = 0; j < 4; ++j) {
                const float4 v = prow[j];
                psi[4 * j + 0] = v.x; psi[4 * j + 1] = v.y;
                psi[4 * j + 2] = v.z; psi[4 * j + 3] = v.w;
            }
        }

        float Ar = 0.f, Ai = 0.f;
#pragma unroll
        for (int k = 0; k < 16; ++k) {
            Ar = fmaf(Ur[k], psi[k], Ar);
            Ai = fmaf(Ui[k], psi[k], Ai);
        }
        float v = Ar * Ar + Ai * Ai;

        // signed WHT butterfly over the 16-lane group
#pragma unroll
        for (int s = 0; s < 4; ++s) {
            const float t = __shfl_xor(v, 1 << s, 64);
            v = fmaf(sgn[s], v, t);
        }
        // lane (8>>q) now holds z_q
        if (p < NP) {
            if (a == 8)      qf[p * 4 + 0] = v;
            else if (a == 4) qf[p * 4 + 1] = v;
            else if (a == 2) qf[p * 4 + 2] = v;
            else if (a == 1) qf[p * 4 + 3] = v;
        }
    }
    __syncthreads();

    // ---- Phase B: GEMV (784 -> 10) + log_softmax
    float acc[10];
#pragma unroll
    for (int k = 0; k < 10; ++k) acc[k] = 0.f;

    for (int f = tid; f < 784; f += 256) {
        const float v = qf[f];
#pragma unroll
        for (int k = 0; k < 10; ++k)
            acc[k] = fmaf(v, Wc[k * 784 + f], acc[k]);
    }

#pragma unroll
    for (int k = 0; k < 10; ++k) {
#pragma unroll
        for (int off = 32; off > 0; off >>= 1)
            acc[k] += __shfl_down(acc[k], off, 64);
    }
    const int wave = tid >> 6;
    const int lane = tid & 63;
    if (lane == 0) {
#pragma unroll
        for (int k = 0; k < 10; ++k) red[wave * 10 + k] = acc[k];
    }
    __syncthreads();

    if (tid < 10)
        logits_s[tid] = bc[tid] + red[tid] + red[10 + tid] + red[20 + tid] + red[30 + tid];
    __syncthreads();

    if (tid < 10) {
        float m = logits_s[0];
#pragma unroll
        for (int jj = 1; jj < 10; ++jj) m = fmaxf(m, logits_s[jj]);
        float se = 0.f;
#pragma unroll
        for (int jj = 0; jj < 10; ++jj) se += __expf(logits_s[jj] - m);
        out[b * 10 + tid] = logits_s[tid] - m - __logf(se);
    }
}

// ---------------------------------------------------------------------------
extern "C" void kernel_launch(void* const* d_in, const int* in_sizes, int n_in,
                              void* d_out, int out_size, void* d_ws, size_t ws_size,
                              hipStream_t stream)
{
    const float* x  = (const float*)d_in[0];   // (B,1,28,28)
    const float* w  = (const float*)d_in[1];   // (L,4,2)
    const float* Wc = (const float*)d_in[2];   // (10,784)
    const float* bc = (const float*)d_in[3];   // (10,)
    float* out = (float*)d_out;                // (B,10)
    float* U   = (float*)d_ws;                 // 512 floats

    const int L = in_sizes[1] / 8;
    const int B = in_sizes[0] / 784;

    setup_U_kernel<<<1, 64, 0, stream>>>(w, L, U);
    quanv_fused_kernel<<<B, 256, 0, stream>>>(x, Wc, bc, U, out);
}